// Round 4
// baseline (3632.950 us; speedup 1.0000x reference)
//
#include <hip/hip_runtime.h>

#define N_ROWS 8192
#define M_ROWS 4096
#define D_DIM  512
#define N_ITERS 100
constexpr size_t NM = (size_t)N_ROWS * (size_t)M_ROWS;
constexpr float FREG   = 0.1f;
constexpr float FI     = 0.5f / (0.5f + 0.1f);     // tau/(tau+reg)
constexpr float A_MARG = 1.0f / (float)N_ROWS;
constexpr float B_MARG = 1.0f / (float)M_ROWS;
#define FIN_BLOCKS 16384                            // NM / (8*256)

// ---------- bf16 helpers (RNE pack) ----------
__device__ __forceinline__ unsigned short f2bf(float f) {
    unsigned int u = __float_as_uint(f);
    u += 0x7fffu + ((u >> 16) & 1u);
    return (unsigned short)(u >> 16);
}
__device__ __forceinline__ float bflo(unsigned int u) { return __uint_as_float(u << 16); }
__device__ __forceinline__ float bfhi(unsigned int u) { return __uint_as_float(u & 0xffff0000u); }
__device__ __forceinline__ unsigned int pack2(float a, float b) {
    return (unsigned int)f2bf(a) | ((unsigned int)f2bf(b) << 16);
}

// async global->LDS, 16B per lane; data lands at lds base + lane*16 (m97/m104)
typedef __attribute__((address_space(1))) void gvoid;
typedef __attribute__((address_space(3))) void lvoid;
__device__ __forceinline__ void async_load16(const void* g, void* l) {
    __builtin_amdgcn_global_load_lds((gvoid*)g, (lvoid*)l, 16, 0, 0);
}

#define FMA8(ac, kk, A, B)                                          \
    ac = fmaf(bflo(kk.x), A.x, ac); ac = fmaf(bfhi(kk.x), A.y, ac); \
    ac = fmaf(bflo(kk.y), A.z, ac); ac = fmaf(bfhi(kk.y), A.w, ac); \
    ac = fmaf(bflo(kk.z), B.x, ac); ac = fmaf(bfhi(kk.z), B.y, ac); \
    ac = fmaf(bflo(kk.w), B.z, ac); ac = fmaf(bfhi(kk.w), B.w, ac);

// ---------- K0: init v = 1/m, maxc = 0 ----------
__global__ void __launch_bounds__(256) init_kernel(float* v, unsigned int* maxc) {
    int t = blockIdx.x * 256 + threadIdx.x;
    if (t < M_ROWS) v[t] = B_MARG;
    if (t == 0) *maxc = 0u;
}

// ---------- K1: per-row min-shift + bf16 cast + sum of squares ----------
__global__ void __launch_bounds__(256) rownorm_kernel(const float* __restrict__ x,
                                                      unsigned short* __restrict__ xn,
                                                      float* __restrict__ x2) {
    int lane = threadIdx.x & 63;
    int row  = blockIdx.x * 4 + (threadIdx.x >> 6);
    const float* p = x + (size_t)row * D_DIM + lane * 8;
    float4 v0 = *(const float4*)p;
    float4 v1 = *(const float4*)(p + 4);
    float a[8] = {v0.x, v0.y, v0.z, v0.w, v1.x, v1.y, v1.z, v1.w};
    float mn = a[0];
#pragma unroll
    for (int t = 1; t < 8; ++t) mn = fminf(mn, a[t]);
#pragma unroll
    for (int o = 32; o >= 1; o >>= 1) mn = fminf(mn, __shfl_xor(mn, o, 64));
    float ss = 0.0f;
#pragma unroll
    for (int t = 0; t < 8; ++t) { a[t] -= mn; ss = fmaf(a[t], a[t], ss); }
#pragma unroll
    for (int o = 32; o >= 1; o >>= 1) ss += __shfl_xor(ss, o, 64);
    uint4 pk;
    pk.x = pack2(a[0], a[1]); pk.y = pack2(a[2], a[3]);
    pk.z = pack2(a[4], a[5]); pk.w = pack2(a[6], a[7]);
    *(uint4*)(xn + (size_t)row * D_DIM + lane * 8) = pk;
    if (lane == 0) x2[row] = ss;
}

// ---------- K2: bf16 MFMA GEMM -> cost (bf16, row-major N x M) + global max ----------
typedef __attribute__((ext_vector_type(8))) short short8;   // 8 bf16 = 4 VGPRs
typedef __attribute__((ext_vector_type(4))) float f32x4;

__global__ void __launch_bounds__(256) gemm_cost_kernel(const unsigned short* __restrict__ xn,
                                                        const unsigned short* __restrict__ yn,
                                                        const float* __restrict__ x2,
                                                        const float* __restrict__ y2,
                                                        unsigned short* __restrict__ cost,
                                                        unsigned int* __restrict__ maxc) {
    __shared__ unsigned short As[128 * 40];   // pad 32->40 to break bank conflicts
    __shared__ unsigned short Bs[128 * 40];
    __shared__ float wred[4];
    int tid = threadIdx.x, lane = tid & 63, w = tid >> 6;
    int wm = w >> 1, wn = w & 1;
    int i0 = blockIdx.x * 128, j0 = blockIdx.y * 128;
    int lr = tid >> 2;      // 0..63 (staging row)
    int lq = tid & 3;       // 0..3  (staging col group of 8)
    f32x4 acc[4][4] = {};
    int m = lane & 15, quad = lane >> 4;

    for (int k0 = 0; k0 < D_DIM; k0 += 32) {
        uint4 a0 = *(const uint4*)(xn + (size_t)(i0 + lr) * D_DIM + k0 + lq * 8);
        uint4 a1 = *(const uint4*)(xn + (size_t)(i0 + lr + 64) * D_DIM + k0 + lq * 8);
        uint4 b0 = *(const uint4*)(yn + (size_t)(j0 + lr) * D_DIM + k0 + lq * 8);
        uint4 b1 = *(const uint4*)(yn + (size_t)(j0 + lr + 64) * D_DIM + k0 + lq * 8);
        __syncthreads();
        *(uint4*)&As[lr * 40 + lq * 8]        = a0;
        *(uint4*)&As[(lr + 64) * 40 + lq * 8] = a1;
        *(uint4*)&Bs[lr * 40 + lq * 8]        = b0;
        *(uint4*)&Bs[(lr + 64) * 40 + lq * 8] = b1;
        __syncthreads();
        short8 af[4], bfr[4];
#pragma unroll
        for (int t = 0; t < 4; ++t) {
            af[t]  = *(const short8*)&As[(wm * 64 + t * 16 + m) * 40 + quad * 8];
            bfr[t] = *(const short8*)&Bs[(wn * 64 + t * 16 + m) * 40 + quad * 8];
        }
#pragma unroll
        for (int tm = 0; tm < 4; ++tm)
#pragma unroll
            for (int tn = 0; tn < 4; ++tn)
                acc[tm][tn] = __builtin_amdgcn_mfma_f32_16x16x32_bf16(af[tm], bfr[tn], acc[tm][tn], 0, 0, 0);
    }

    float mymax = 0.0f;
#pragma unroll
    for (int tm = 0; tm < 4; ++tm) {
#pragma unroll
        for (int tn = 0; tn < 4; ++tn) {
            int col = j0 + wn * 64 + tn * 16 + m;
            float yv = y2[col];
#pragma unroll
            for (int t = 0; t < 4; ++t) {
                int row = i0 + wm * 64 + tm * 16 + quad * 4 + t;
                float c = fmaxf(x2[row] + yv - 2.0f * acc[tm][tn][t], 0.0f);
                mymax = fmaxf(mymax, c);
                cost[(size_t)row * M_ROWS + col] = f2bf(c);
            }
        }
    }
#pragma unroll
    for (int o = 32; o >= 1; o >>= 1) mymax = fmaxf(mymax, __shfl_xor(mymax, o, 64));
    if (lane == 0) wred[w] = mymax;
    __syncthreads();
    if (tid == 0) {
        float mx = fmaxf(fmaxf(wred[0], wred[1]), fmaxf(wred[2], wred[3]));
        atomicMax(maxc, __float_as_uint(mx));
    }
}

// ---------- K3: K = exp(-cost*10/maxc) in place (bf16) + transposed copy KT ----------
__global__ void __launch_bounds__(256) expT_kernel(unsigned short* __restrict__ Kmat,
                                                   unsigned short* __restrict__ KTmat,
                                                   const unsigned int* __restrict__ maxcb) {
    __shared__ unsigned int tl[64 * 33];
    float scale = -(1.0f / FREG) / __uint_as_float(*maxcb);
    int i0 = blockIdx.x * 64, j0 = blockIdx.y * 64;
    int tid = threadIdx.x;
    int b = tid & 7;        // col group (8 cols)
    int rp = tid >> 3;      // 0..31 row pair
    size_t base0 = (size_t)(i0 + 2 * rp) * M_ROWS + j0 + b * 8;
    uint4 c0 = *(const uint4*)(Kmat + base0);
    uint4 c1 = *(const uint4*)(Kmat + base0 + M_ROWS);
    unsigned int cc0[4] = {c0.x, c0.y, c0.z, c0.w};
    unsigned int cc1[4] = {c1.x, c1.y, c1.z, c1.w};
    float k0[8], k1[8];
#pragma unroll
    for (int t = 0; t < 4; ++t) {
        k0[2 * t]     = expf(bflo(cc0[t]) * scale);
        k0[2 * t + 1] = expf(bfhi(cc0[t]) * scale);
        k1[2 * t]     = expf(bflo(cc1[t]) * scale);
        k1[2 * t + 1] = expf(bfhi(cc1[t]) * scale);
    }
    uint4 o0, o1;
    o0.x = pack2(k0[0], k0[1]); o0.y = pack2(k0[2], k0[3]);
    o0.z = pack2(k0[4], k0[5]); o0.w = pack2(k0[6], k0[7]);
    o1.x = pack2(k1[0], k1[1]); o1.y = pack2(k1[2], k1[3]);
    o1.z = pack2(k1[4], k1[5]); o1.w = pack2(k1[6], k1[7]);
    *(uint4*)(Kmat + base0)          = o0;
    *(uint4*)(Kmat + base0 + M_ROWS) = o1;
#pragma unroll
    for (int t = 0; t < 8; ++t)
        tl[(b * 8 + t) * 33 + rp] = pack2(k0[t], k1[t]);
    __syncthreads();
    int c = tid >> 2, q = tid & 3;
    unsigned int o[8];
#pragma unroll
    for (int k = 0; k < 8; ++k) o[k] = tl[c * 33 + q * 8 + k];
    uint4 w0 = {o[0], o[1], o[2], o[3]};
    uint4 w1 = {o[4], o[5], o[6], o[7]};
    size_t ob = (size_t)(j0 + c) * N_ROWS + i0 + q * 16;
    *(uint4*)(KTmat + ob)     = w0;
    *(uint4*)(KTmat + ob + 8) = w1;
}

// ---------- K4a: u = (a / (K v))^fi ----------
// 512 blocks x 4 waves, 4 rows/wave. K rows staged to LDS via global_load_lds
// (double-buffered 4KB chunks, 512 cols/segment); v held in 64 VGPRs.
// MLP no longer VGPR-bound: ~4KB in flight per wave -> L3-BW-bound.
__global__ void __launch_bounds__(256, 2) u_step_kernel(const unsigned short* __restrict__ Km,
                                                        const float* __restrict__ v,
                                                        float* __restrict__ u) {
    __shared__ __align__(16) char buf[4][2][4096];   // 32 KB: [wave][slot][4 rows x 1KB]
    int tid = threadIdx.x, lane = tid & 63, w = tid >> 6;
    int r0 = blockIdx.x * 16 + w * 4;
    float4 va[8], vb[8];                              // v: 8 segments x 8 floats/lane
    const float4* vp = (const float4*)v;
#pragma unroll
    for (int s = 0; s < 8; ++s) {
        va[s] = vp[s * 128 + lane * 2];
        vb[s] = vp[s * 128 + lane * 2 + 1];
    }
    char* wbuf = &buf[w][0][0];
    const unsigned short* kbase = Km + (size_t)r0 * M_ROWS + lane * 8;
    float acc[4] = {0.0f, 0.0f, 0.0f, 0.0f};

#define STAGE_U(ss) {                                              \
        const unsigned short* sp = kbase + (ss) * 512;             \
        char* dst = wbuf + ((ss) & 1) * 4096;                      \
        async_load16(sp,              dst);                        \
        async_load16(sp +     M_ROWS, dst + 1024);                 \
        async_load16(sp + 2 * M_ROWS, dst + 2048);                 \
        async_load16(sp + 3 * M_ROWS, dst + 3072); }

    STAGE_U(0);
#pragma unroll
    for (int s = 0; s < 8; ++s) {
        if (s < 7) { STAGE_U(s + 1); asm volatile("s_waitcnt vmcnt(4)" ::: "memory"); }
        else       { asm volatile("s_waitcnt vmcnt(0)" ::: "memory"); }
        const char* src = wbuf + (s & 1) * 4096 + lane * 16;
        uint4 k0 = *(const uint4*)(src);
        uint4 k1 = *(const uint4*)(src + 1024);
        uint4 k2 = *(const uint4*)(src + 2048);
        uint4 k3 = *(const uint4*)(src + 3072);
        float4 A = va[s], B = vb[s];
        FMA8(acc[0], k0, A, B);
        FMA8(acc[1], k1, A, B);
        FMA8(acc[2], k2, A, B);
        FMA8(acc[3], k3, A, B);
    }
#undef STAGE_U
#pragma unroll
    for (int i = 0; i < 4; ++i) {
        float d = acc[i];
#pragma unroll
        for (int o = 32; o >= 1; o >>= 1) d += __shfl_xor(d, o, 64);
        if (lane == 0) u[r0 + i] = powf(A_MARG / d, FI);
    }
}

// ---------- K4b: v = (b / (K^T u))^fi ----------
// 512 blocks x 4 waves, 2 rows/wave; u held in 128 VGPRs; 2KB chunks dbuf.
__global__ void __launch_bounds__(256, 1) v_step_kernel(const unsigned short* __restrict__ KTm,
                                                        const float* __restrict__ u,
                                                        float* __restrict__ vout) {
    __shared__ __align__(16) char buf[4][2][2048];   // 16 KB
    int tid = threadIdx.x, lane = tid & 63, w = tid >> 6;
    int r0 = blockIdx.x * 8 + w * 2;
    float4 ua[16], ub[16];                            // u: 16 segments x 8 floats/lane
    const float4* up = (const float4*)u;
#pragma unroll
    for (int s = 0; s < 16; ++s) {
        ua[s] = up[s * 128 + lane * 2];
        ub[s] = up[s * 128 + lane * 2 + 1];
    }
    char* wbuf = &buf[w][0][0];
    const unsigned short* kbase = KTm + (size_t)r0 * N_ROWS + lane * 8;
    float acc[2] = {0.0f, 0.0f};

#define STAGE_V(ss) {                                              \
        const unsigned short* sp = kbase + (ss) * 512;             \
        char* dst = wbuf + ((ss) & 1) * 2048;                      \
        async_load16(sp,          dst);                            \
        async_load16(sp + N_ROWS, dst + 1024); }

    STAGE_V(0);
#pragma unroll
    for (int s = 0; s < 16; ++s) {
        if (s < 15) { STAGE_V(s + 1); asm volatile("s_waitcnt vmcnt(2)" ::: "memory"); }
        else        { asm volatile("s_waitcnt vmcnt(0)" ::: "memory"); }
        const char* src = wbuf + (s & 1) * 2048 + lane * 16;
        uint4 k0 = *(const uint4*)(src);
        uint4 k1 = *(const uint4*)(src + 1024);
        float4 A = ua[s], B = ub[s];
        FMA8(acc[0], k0, A, B);
        FMA8(acc[1], k1, A, B);
    }
#undef STAGE_V
#pragma unroll
    for (int i = 0; i < 2; ++i) {
        float d = acc[i];
#pragma unroll
        for (int o = 32; o >= 1; o >>= 1) d += __shfl_xor(d, o, 64);
        if (lane == 0) vout[r0 + i] = powf(B_MARG / d, FI);
    }
}

// ---------- K5: pi = flow^T (KT layout, coalesced), per-block dist partials ----------
__global__ void __launch_bounds__(256) finalize_kernel(const unsigned short* __restrict__ KTm,
                                                       const float* __restrict__ u,
                                                       const float* __restrict__ v,
                                                       const unsigned int* __restrict__ maxcb,
                                                       float* __restrict__ out,
                                                       float* __restrict__ part) {
    __shared__ float red[4];
    int tid = threadIdx.x, lane = tid & 63;
    size_t base = ((size_t)blockIdx.x * 256 + tid) * 8;
    int mrow = (int)(base >> 13);
    int n    = (int)(base & 8191);
    float cscale = -FREG * __uint_as_float(*maxcb);   // cost = -reg*maxc*ln(K)
    uint4 kk = *(const uint4*)(KTm + base);
    float4 u0 = *(const float4*)(u + n);
    float4 u1 = *(const float4*)(u + n + 4);
    float vm = v[mrow];
    float kv[8] = {bflo(kk.x), bfhi(kk.x), bflo(kk.y), bfhi(kk.y),
                   bflo(kk.z), bfhi(kk.z), bflo(kk.w), bfhi(kk.w)};
    float uu[8] = {u0.x, u0.y, u0.z, u0.w, u1.x, u1.y, u1.z, u1.w};
    float fl[8];
    float ds = 0.0f;
#pragma unroll
    for (int t = 0; t < 8; ++t) {
        fl[t] = uu[t] * kv[t] * vm;
        ds = fmaf(cscale * logf(kv[t]), fl[t], ds);
    }
    float4 w0 = {fl[0], fl[1], fl[2], fl[3]};
    float4 w1 = {fl[4], fl[5], fl[6], fl[7]};
    *(float4*)(out + base)     = w0;
    *(float4*)(out + base + 4) = w1;
#pragma unroll
    for (int o = 32; o >= 1; o >>= 1) ds += __shfl_xor(ds, o, 64);
    if (lane == 0) red[tid >> 6] = ds;
    __syncthreads();
    if (tid == 0) part[blockIdx.x] = red[0] + red[1] + red[2] + red[3];
}

// ---------- K6: reduce partials -> dist ----------
__global__ void __launch_bounds__(256) reduce_dist_kernel(const float* __restrict__ part,
                                                          float* __restrict__ dist) {
    __shared__ float red[4];
    int tid = threadIdx.x, lane = tid & 63;
    float s = 0.0f;
    for (int i = tid; i < FIN_BLOCKS; i += 256) s += part[i];
#pragma unroll
    for (int o = 32; o >= 1; o >>= 1) s += __shfl_xor(s, o, 64);
    if (lane == 0) red[tid >> 6] = s;
    __syncthreads();
    if (tid == 0) *dist = red[0] + red[1] + red[2] + red[3];
}

// ---------- host ----------
extern "C" void kernel_launch(void* const* d_in, const int* in_sizes, int n_in,
                              void* d_out, int out_size, void* d_ws, size_t ws_size,
                              hipStream_t stream) {
    const float* x = (const float*)d_in[0];
    const float* y = (const float*)d_in[1];
    float* out = (float*)d_out;
    char* ws = (char*)d_ws;

    unsigned short* Kmat = (unsigned short*)(ws);                 // 64 MiB (cost, then K in place)
    unsigned short* KT   = (unsigned short*)(ws + 67108864);      // 64 MiB
    unsigned short* xn   = (unsigned short*)(ws + 134217728);     // 8 MiB (dead after gemm)
    unsigned short* yn   = (unsigned short*)(ws + 142606336);     // 4 MiB
    float* x2            = (float*)(ws + 146800640);
    float* y2            = (float*)(ws + 146833408);
    float* u             = (float*)(ws + 146849792);
    float* v             = (float*)(ws + 146882560);
    unsigned int* maxc   = (unsigned int*)(ws + 146898944);
    float* part          = (float*)(ws + 134217728);              // reuse dead xn region
    float* dist = out + NM;

    init_kernel<<<16, 256, 0, stream>>>(v, maxc);
    rownorm_kernel<<<N_ROWS / 4, 256, 0, stream>>>(x, xn, x2);
    rownorm_kernel<<<M_ROWS / 4, 256, 0, stream>>>(y, yn, y2);
    gemm_cost_kernel<<<dim3(N_ROWS / 128, M_ROWS / 128), 256, 0, stream>>>(xn, yn, x2, y2, Kmat, maxc);
    expT_kernel<<<dim3(N_ROWS / 64, M_ROWS / 64), 256, 0, stream>>>(Kmat, KT, maxc);

    for (int it = 0; it < N_ITERS; ++it) {
        u_step_kernel<<<512, 256, 0, stream>>>(Kmat, v, u);
        v_step_kernel<<<512, 256, 0, stream>>>(KT, u, v);
    }

    finalize_kernel<<<FIN_BLOCKS, 256, 0, stream>>>(KT, u, v, maxc, out, part);
    reduce_dist_kernel<<<1, 256, 0, stream>>>(part, dist);
}